// Round 6
// baseline (114.482 us; speedup 1.0000x reference)
//
#include <hip/hip_runtime.h>
#include <cstddef>

// B=8, Cin=32, D=16, H=W=32 -> ConvTranspose3d(32->64, k=3, s=2, p=1)
// -> mean over depth (D'=31) -> +bias -> softmax over C=64 -> tanh*2.
// Output (8, 64, 1, 63, 63) fp32.
//
// Depth-mean folds into weights: A0 = S - x[0], A1 = S, A2 = S - x[15]
// (S = sum_d x), m = cb + sum_kd Tconv2d(A_kd, w/31).
// Parity classes (oh&1, ow&1): taps/cin = 3 (EE), 6 (EO/OE), 12 (OO).
//
// ROUND-6: equal-work waves. R5 counters showed no spill, vector-path fixed
// (VALUBusy 14->35%), but dur stuck at 46us: latency exposure x imbalance
// (EE:EO:OE:OO = 3:6:6:12 taps; even-oh blocks half the work of odd-oh).
// Now each wave's pixel count is inversely prop. to taps -> 48 FMA-units/cin
// for EVERY wave: EE=16px, EO/OE=8px, OO=4px. Block = (b, row-pair, half):
// 9 waves (576 thr) cover one even + one odd row half; LDS stages rows
// rr, rr+1 once. 512 blocks x 9 equal waves, unroll-2 cin pipeline.
// (Also identified: 47us of dur is the harness's 256MiB d_ws 0xAA fill —
// untouchable floor.)

namespace {
constexpr int OFF_EE = 0;                          // T=3  [tap][cin][cout]
constexpr int OFF_EO = 32 * 64 * 3;                // T=6
constexpr int OFF_OE = OFF_EO + 32 * 64 * 6;       // T=6
constexpr int OFF_OO = OFF_OE + 32 * 64 * 6;       // T=12
constexpr int OFF_CB = OFF_OO + 32 * 64 * 12;      // cb[64]
constexpr int OFF_A  = OFF_CB + 64;                // A'[b][ih][kd][cin][w]
}

// ---------------- prep: weight transform (+bias) AND depth reduce ----------
extern "C" __global__ __launch_bounds__(256) void k_prep(
    const float* __restrict__ x, const float* __restrict__ w,
    const float* __restrict__ conv_bias, const float* __restrict__ bias,
    float* __restrict__ ws) {
  const int bid = blockIdx.x;
  const int tid = threadIdx.x;
  if (bid < 8) {
    int t = bid * 256 + tid;                       // cin*64+cout over 2048
    if (t < 64) ws[OFF_CB + t] = conv_bias[t] + bias[t];
    if (t >= 32 * 64) return;
    const int cin = t >> 6, cout = t & 63;
    const float s = 1.0f / 31.0f;
    const float* src = w + t * 27;                 // (Cin, Cout, 3,3,3)
    float wv[27];
#pragma unroll
    for (int i = 0; i < 27; ++i) wv[i] = src[i] * s;
    // transposed tables: ws[toff + (tap*32 + cin)*64 + cout]
#pragma unroll
    for (int kd = 0; kd < 3; ++kd) {
      ws[OFF_EE + ((kd)*32 + cin) * 64 + cout]           = wv[kd * 9 + 4]; // (1,1)
      ws[OFF_EO + ((kd * 2 + 0) * 32 + cin) * 64 + cout] = wv[kd * 9 + 3]; // (1,0) a[j+1]
      ws[OFF_EO + ((kd * 2 + 1) * 32 + cin) * 64 + cout] = wv[kd * 9 + 5]; // (1,2) a[j]
      ws[OFF_OE + ((kd * 2 + 0) * 32 + cin) * 64 + cout] = wv[kd * 9 + 1]; // (0,1) rowA
      ws[OFF_OE + ((kd * 2 + 1) * 32 + cin) * 64 + cout] = wv[kd * 9 + 7]; // (2,1) rowB
      ws[OFF_OO + ((kd * 4 + 0) * 32 + cin) * 64 + cout] = wv[kd * 9 + 0]; // rA a[j+1]
      ws[OFF_OO + ((kd * 4 + 1) * 32 + cin) * 64 + cout] = wv[kd * 9 + 2]; // rA a[j]
      ws[OFF_OO + ((kd * 4 + 2) * 32 + cin) * 64 + cout] = wv[kd * 9 + 6]; // rB a[j+1]
      ws[OFF_OO + ((kd * 4 + 3) * 32 + cin) * 64 + cout] = wv[kd * 9 + 8]; // rB a[j]
    }
  } else {
    // depth reduce, d-split across lane halves: 131072 threads
    int t = (bid - 8) * 256 + tid;
    int g = t >> 6;
    int lane = t & 63;
    int dh = lane >> 5;
    int o = g * 32 + (lane & 31);                  // float4 work index
    int bc = o >> 8;                               // b*32+cin
    int c4 = o & 255;                              // ih*8 + w4
    int b = bc >> 5, cin = bc & 31;
    int ih = c4 >> 3, w4 = c4 & 7;
    const float4* xp = (const float4*)x + (size_t)bc * 4096 + c4;
    float4 vv[8];
#pragma unroll
    for (int j = 0; j < 8; ++j) vv[j] = xp[(dh * 8 + j) * 256];
    float sx = 0.f, sy = 0.f, sz = 0.f, sw = 0.f;
#pragma unroll
    for (int j = 0; j < 8; ++j) { sx += vv[j].x; sy += vv[j].y; sz += vv[j].z; sw += vv[j].w; }
    float fx = sx + __shfl_xor(sx, 32);
    float fy = sy + __shfl_xor(sy, 32);
    float fz = sz + __shfl_xor(sz, 32);
    float fw = sw + __shfl_xor(sw, 32);
    // A'[b][ih][kd][cin][w]: f4 dst = ((b*32+ih)*3+kd)*256 + cin*8 + w4
    float4* Af = (float4*)(ws + OFF_A);
    size_t base = ((size_t)(b * 32 + ih) * 3) * 256 + cin * 8 + w4;
    if (dh == 0) {
      float4 a0; a0.x = fx - vv[0].x; a0.y = fy - vv[0].y; a0.z = fz - vv[0].z; a0.w = fw - vv[0].w;
      Af[base] = a0;                               // kd=0 (drops d=0)
      float4 a1; a1.x = fx; a1.y = fy; a1.z = fz; a1.w = fw;
      Af[base + 256] = a1;                         // kd=1
    } else {
      float4 a2; a2.x = fx - vv[7].x; a2.y = fy - vv[7].y; a2.z = fz - vv[7].z; a2.w = fw - vv[7].w;
      Af[base + 512] = a2;                         // kd=2 (drops d=15)
    }
  }
}

// ---------------- main ----------------
// alds[0] = input row rr (kh=1 for even oh, kh=2 "rowB" for odd oh)
// alds[1] = input row rr+1 (kh=0 "rowA" for odd oh)
template <int RP, int CP, int NPIX>
__device__ __forceinline__ void conv_class(const float* __restrict__ ws,
                                           float* __restrict__ out,
                                           const float (&alds)[2][3][32][32],
                                           int b, int oh, int j0, int npx,
                                           int lane) {
  constexpr int T = 3 * (RP + 1) * (CP + 1);
  constexpr int toff = RP ? (CP ? OFF_OO : OFF_OE) : (CP ? OFF_EO : OFF_EE);
  const float* wt = ws + toff;
  const int lastIdx = (j0 + NPIX < 32) ? j0 + NPIX : 31;  // CP=1 tail clamp

  float wcur[T], wnxt[T];
#pragma unroll
  for (int t = 0; t < T; ++t) wcur[t] = wt[(t * 32) * 64 + lane];

  float acc[NPIX];
#pragma unroll
  for (int p = 0; p < NPIX; ++p) acc[p] = 0.f;

#pragma unroll 2
  for (int ci = 0; ci < 32; ++ci) {
    if (ci < 31) {                                  // prefetch next cin weights
#pragma unroll
      for (int t = 0; t < T; ++t) wnxt[t] = wt[(t * 32 + ci + 1) * 64 + lane];
    }
#pragma unroll
    for (int kd = 0; kd < 3; ++kd) {
      if constexpr (RP == 0 && CP == 0) {
        const float w1 = wcur[kd];
#pragma unroll
        for (int p = 0; p < NPIX; ++p)
          acc[p] = fmaf(alds[0][kd][ci][j0 + p], w1, acc[p]);
      } else if constexpr (RP == 0 && CP == 1) {
        float av[NPIX + 1];
#pragma unroll
        for (int k = 0; k < NPIX; ++k) av[k] = alds[0][kd][ci][j0 + k];
        av[NPIX] = alds[0][kd][ci][lastIdx];
        const float w0 = wcur[kd * 2], w2 = wcur[kd * 2 + 1];
#pragma unroll
        for (int p = 0; p < NPIX; ++p) {
          acc[p] = fmaf(av[p + 1], w0, acc[p]);
          acc[p] = fmaf(av[p],     w2, acc[p]);
        }
      } else if constexpr (RP == 1 && CP == 0) {
        const float wa = wcur[kd * 2], wb = wcur[kd * 2 + 1];
#pragma unroll
        for (int p = 0; p < NPIX; ++p) {
          acc[p] = fmaf(alds[1][kd][ci][j0 + p], wa, acc[p]);  // kh=0 row
          acc[p] = fmaf(alds[0][kd][ci][j0 + p], wb, acc[p]);  // kh=2 row
        }
      } else {
        float av[NPIX + 1], bv[NPIX + 1];
#pragma unroll
        for (int k = 0; k < NPIX; ++k) {
          av[k] = alds[1][kd][ci][j0 + k];
          bv[k] = alds[0][kd][ci][j0 + k];
        }
        av[NPIX] = alds[1][kd][ci][lastIdx];
        bv[NPIX] = alds[0][kd][ci][lastIdx];
        const float w00 = wcur[kd * 4 + 0], w02 = wcur[kd * 4 + 1];
        const float w20 = wcur[kd * 4 + 2], w22 = wcur[kd * 4 + 3];
#pragma unroll
        for (int p = 0; p < NPIX; ++p) {
          acc[p] = fmaf(av[p + 1], w00, acc[p]);
          acc[p] = fmaf(av[p],     w02, acc[p]);
          acc[p] = fmaf(bv[p + 1], w20, acc[p]);
          acc[p] = fmaf(bv[p],     w22, acc[p]);
        }
      }
    }
    if (ci < 31) {
#pragma unroll
      for (int t = 0; t < T; ++t) wcur[t] = wnxt[t];
    }
  }

  // bias + in-wave softmax over lanes (=couts), NPIX interleaved chains
  const float cbv = ws[OFF_CB + lane];
  float mx[NPIX], sm[NPIX];
#pragma unroll
  for (int p = 0; p < NPIX; ++p) { acc[p] += cbv; mx[p] = acc[p]; }
#pragma unroll
  for (int s = 1; s < 64; s <<= 1) {
#pragma unroll
    for (int p = 0; p < NPIX; ++p) mx[p] = fmaxf(mx[p], __shfl_xor(mx[p], s));
  }
#pragma unroll
  for (int p = 0; p < NPIX; ++p) { acc[p] = __expf(acc[p] - mx[p]); sm[p] = acc[p]; }
#pragma unroll
  for (int s = 1; s < 64; s <<= 1) {
#pragma unroll
    for (int p = 0; p < NPIX; ++p) sm[p] += __shfl_xor(sm[p], s);
  }
  float* op = out + ((size_t)(b * 64 + lane) * 63 + oh) * 63;
#pragma unroll
  for (int p = 0; p < NPIX; ++p) {
    if (p < npx) {
      float sv = acc[p] / sm[p];
      float e2 = __expf(2.0f * sv);                 // 2*tanh(s) = 2 - 4/(e^2s+1)
      op[2 * (j0 + p) + CP] = 2.0f - 4.0f / (e2 + 1.0f);
    }
  }
}

extern "C" __global__ __launch_bounds__(576, 4) void k_main(
    const float* __restrict__ ws, float* __restrict__ out) {
  __shared__ float alds[2][3][32][32];              // 24.6 KB
  const int gx = blockIdx.x;                        // rr*2 + h, 0..63
  const int b  = blockIdx.y;                        // 0..7
  const int rr = gx >> 1;                           // row pair: ohE=2rr, ohO=2rr+1
  const int h  = gx & 1;                            // pixel half
  const int tid = threadIdx.x;

  // stage rows rr and rr+1 (vector float4, lane-linear LDS writes)
  const float4* Af = (const float4*)(ws + OFF_A);
  {
    const float4* s0 = Af + (size_t)((b * 32 + rr) * 3) * 256;
    float4* d0 = (float4*)&alds[0][0][0][0];
    for (int i = tid; i < 768; i += 576) d0[i] = s0[i];
  }
  if (rr < 31) {
    const float4* s1 = Af + (size_t)((b * 32 + rr + 1) * 3) * 256;
    float4* d1 = (float4*)&alds[1][0][0][0];
    for (int i = tid; i < 768; i += 576) d1[i] = s1[i];
  }
  __syncthreads();

  const int wid  = __builtin_amdgcn_readfirstlane(tid >> 6);  // 0..8
  const int lane = tid & 63;                        // cout
  const int ohE = 2 * rr, ohO = 2 * rr + 1;

  // equal-work map: 48 FMA-units/cin for every wave
  if (wid == 0) {                                   // EE: 16 px
    conv_class<0, 0, 16>(ws, out, alds, b, ohE, h * 16, 16, lane);
  } else if (wid <= 2) {                            // EO: 8 px (tail 7)
    const int g = h * 2 + (wid - 1);
    conv_class<0, 1, 8>(ws, out, alds, b, ohE, g * 8, (g == 3) ? 7 : 8, lane);
  } else if (wid <= 4) {                            // OE: 8 px
    if (rr < 31) {
      const int g = h * 2 + (wid - 3);
      conv_class<1, 0, 8>(ws, out, alds, b, ohO, g * 8, 8, lane);
    }
  } else {                                          // OO: 4 px (tail 3)
    if (rr < 31) {
      const int s = h * 4 + (wid - 5);
      conv_class<1, 1, 4>(ws, out, alds, b, ohO, s * 4, (s == 7) ? 3 : 4, lane);
    }
  }
}

extern "C" void kernel_launch(void* const* d_in, const int* in_sizes, int n_in,
                              void* d_out, int out_size, void* d_ws,
                              size_t ws_size, hipStream_t stream) {
  const float* x  = (const float*)d_in[0];
  const float* w  = (const float*)d_in[1];
  const float* cb = (const float*)d_in[2];
  const float* bs = (const float*)d_in[3];
  float* ws  = (float*)d_ws;
  float* out = (float*)d_out;

  hipLaunchKernelGGL(k_prep, dim3(520), dim3(256), 0, stream, x, w, cb, bs, ws);
  hipLaunchKernelGGL(k_main, dim3(64, 8), dim3(576), 0, stream, ws, out);
}

// Round 8
// 81.186 us; speedup vs baseline: 1.4101x; 1.4101x over previous
//
#include <hip/hip_runtime.h>
#include <hip/hip_bf16.h>
#include <cstddef>

// B=8, Cin=32, D=16, H=W=32 -> ConvTranspose3d(32->64, k=3, s=2, p=1)
// -> mean over depth (D'=31) -> +bias -> softmax over C=64 -> tanh*2.
// Output (8, 64, 1, 63, 63) fp32.
//
// Depth-mean folds into weights: A0 = S - x[0] (kd=0), A1 = S (kd=1),
// A2 = S - x[15] (kd=2);  m = cb + sum_kd Tconv2d(A_kd, w/31).
// Parity classes (oh&1, ow&1): spatial taps NT = 1 (EE), 2 (EO), 2 (OE), 4 (OO);
// K = NT*96 (96 = 3 kd x 32 cin per tap).
//
// ROUND-8 (= round-7 resubmit; GPU acquisition timed out, kernel unmeasured):
// this is a GEMM -> MFMA (bf16 16x16x32). Rounds 2-6 hit the VALU feed-rate
// wall (~46us) regardless of operand placement. Now:
//  - panels P[b][ih][iw][kd*32+cin] bf16: im2col row = contiguous 192B vector
//  - weights pre-packed in EXACT A-frag lane order -> A-frag = 1 coalesced
//    global_load_dwordx4; B-frag = 16B/lane gather from panel
//  - wave = one 16-pixel tile x all 64 couts: 4 f32x4 accs, 12..48 MFMAs,
//    no LDS, no barriers; softmax = in-lane(16) + shfl_xor(16,32); 2016 waves.
// Frag layouts (m89-verified family): A: m=lane&15, k=(lane>>4)*8+j;
// B: n=lane&15, k=(lane>>4)*8+j; D: col(n)=lane&15, row(m)=(lane>>4)*4+reg.

typedef __attribute__((ext_vector_type(8))) __bf16 bf16x8;
typedef __attribute__((ext_vector_type(4))) float f32x4;

namespace {
// ws byte layout
constexpr int WPACK_B = 0;         // bf16[55296]: EE@0 EO@6144 OE@18432 OO@30720
constexpr int CB_B    = 131072;    // f32[64]
constexpr int PANEL_B = 139264;    // bf16[8*32*32*96] = 1.5 MB
__device__ __constant__ int WOFF[4] = {0, 6144, 18432, 30720};
}

__device__ __forceinline__ uint f2bfu(float f) {
  __hip_bfloat16 h = __float2bfloat16(f);
  return (uint)*reinterpret_cast<unsigned short*>(&h);
}

// ---------------- prep: weight pack + panel build ----------------
extern "C" __global__ __launch_bounds__(256) void k_prep(
    const float* __restrict__ x, const float* __restrict__ w,
    const float* __restrict__ conv_bias, const float* __restrict__ bias,
    float* __restrict__ ws) {
  const int bid = blockIdx.x;
  const int tid = threadIdx.x;
  unsigned short* wpk = (unsigned short*)ws;
  float* cb = (float*)((char*)ws + CB_B);
  unsigned short* panel = (unsigned short*)((char*)ws + PANEL_B);

  if (bid < 8) {
    // ---- weight pack: t = cin*64 + cout over 2048 ----
    int t = bid * 256 + tid;
    if (t < 64) cb[t] = conv_bias[t] + bias[t];
    const int cin = t >> 6, cout = t & 63;
    const float s = 1.0f / 31.0f;
    const float* src = w + t * 27;               // (Cin, Cout, kd, kh, kw)
    float wv[27];
#pragma unroll
    for (int i = 0; i < 27; ++i) wv[i] = src[i] * s;
    const int lane = ((cin >> 3) << 4) + (cout & 15);
    const int j = cin & 7;
    const int m16 = cout >> 4;
    // put(class, KC, tap, kd, value): frag-order index
    auto put = [&](int cls, int KC, int tap, int kd, float v) {
      int idx = WOFF[cls] + (((m16 * KC + tap * 3 + kd) * 64) + lane) * 8 + j;
      wpk[idx] = (unsigned short)f2bfu(v);
    };
#pragma unroll
    for (int kd = 0; kd < 3; ++kd) {
      put(0, 3,  0, kd, wv[kd * 9 + 4]);         // EE: (kh1,kw1)
      put(1, 6,  0, kd, wv[kd * 9 + 3]);         // EO tap0: kw0 (iw=j+1)
      put(1, 6,  1, kd, wv[kd * 9 + 5]);         // EO tap1: kw2 (iw=j)
      put(2, 6,  0, kd, wv[kd * 9 + 1]);         // OE tap0: kh0 (ihA)
      put(2, 6,  1, kd, wv[kd * 9 + 7]);         // OE tap1: kh2 (ihB)
      put(3, 12, 0, kd, wv[kd * 9 + 0]);         // OO: (kh0,kw0) ihA,j+1
      put(3, 12, 1, kd, wv[kd * 9 + 2]);         // OO: (kh0,kw2) ihA,j
      put(3, 12, 2, kd, wv[kd * 9 + 6]);         // OO: (kh2,kw0) ihB,j+1
      put(3, 12, 3, kd, wv[kd * 9 + 8]);         // OO: (kh2,kw2) ihB,j
    }
  } else {
    // ---- panel build: block = (b, ih); depth-reduce + transpose ----
    __shared__ float slds[3][32][33];
    const int p = bid - 8;
    const int b = p >> 5, ih = p & 31;
    {
      const int cin = tid >> 3, w4 = tid & 7;
      const float* xb = x + ((size_t)(b * 32 + cin) * 16) * 1024 + ih * 32 + w4 * 4;
      float4 f0 = *(const float4*)xb;
      float sx = f0.x, sy = f0.y, sz = f0.z, sw = f0.w;
#pragma unroll
      for (int d = 1; d < 15; ++d) {
        float4 v = *(const float4*)(xb + d * 1024);
        sx += v.x; sy += v.y; sz += v.z; sw += v.w;
      }
      float4 f15 = *(const float4*)(xb + 15 * 1024);
      sx += f15.x; sy += f15.y; sz += f15.z; sw += f15.w;
      const int c0 = w4 * 4;
      slds[0][cin][c0 + 0] = sx - f0.x;  slds[1][cin][c0 + 0] = sx;  slds[2][cin][c0 + 0] = sx - f15.x;
      slds[0][cin][c0 + 1] = sy - f0.y;  slds[1][cin][c0 + 1] = sy;  slds[2][cin][c0 + 1] = sy - f15.y;
      slds[0][cin][c0 + 2] = sz - f0.z;  slds[1][cin][c0 + 2] = sz;  slds[2][cin][c0 + 2] = sz - f15.z;
      slds[0][cin][c0 + 3] = sw - f0.w;  slds[1][cin][c0 + 3] = sw;  slds[2][cin][c0 + 3] = sw - f15.w;
    }
    __syncthreads();
    {
      const int iw = tid >> 3, g = tid & 7;      // 8 threads cover 96 bf16/row
      uint* dst = (uint*)(panel + ((size_t)((b * 32 + ih) * 32) + iw) * 96) + g * 6;
#pragma unroll
      for (int mm = 0; mm < 6; ++mm) {
        int k0 = g * 12 + mm * 2;
        uint lo = f2bfu(slds[k0 >> 5][k0 & 31][iw]);
        uint hi = f2bfu(slds[(k0 + 1) >> 5][(k0 + 1) & 31][iw]);
        dst[mm] = lo | (hi << 16);
      }
    }
  }
}

// ---------------- main: one wave per 16-pixel tile ----------------
template <int CLS>
__device__ __forceinline__ void unit_body(const unsigned short* __restrict__ wpk,
                                          const unsigned short* __restrict__ panel,
                                          const float* __restrict__ cb,
                                          float* __restrict__ out,
                                          int b, int oh, int ihA, int ihB,
                                          int pt, int lane) {
  constexpr int NT = (CLS == 0) ? 1 : (CLS == 3 ? 4 : 2);
  constexpr int KC = NT * 3;
  const int p15 = lane & 15, l4 = lane >> 4;
  const int jbase = pt * 16;
  const int laneB = p15 * 96 + l4 * 8;           // bf16 units within panel rows
  const unsigned short* wcls = wpk + WOFF[CLS] + lane * 8;

  f32x4 acc0 = {0,0,0,0}, acc1 = {0,0,0,0}, acc2 = {0,0,0,0}, acc3 = {0,0,0,0};

#pragma unroll
  for (int tap = 0; tap < NT; ++tap) {
    int ih, jo;
    if      constexpr (CLS == 0) { ih = ihA; jo = 0; }
    else if constexpr (CLS == 1) { ih = ihA; jo = (tap == 0) ? 1 : 0; }
    else if constexpr (CLS == 2) { ih = (tap == 0) ? ihA : ihB; jo = 0; }
    else { ih = (tap < 2) ? ihA : ihB; jo = (tap & 1) ? 0 : 1; }

    const unsigned short* bp =
        panel + ((size_t)((b * 32 + ih) * 32) + jbase + jo) * 96 + laneB;
    bf16x8 B0 = *reinterpret_cast<const bf16x8*>(bp);
    bf16x8 B1 = *reinterpret_cast<const bf16x8*>(bp + 32);
    bf16x8 B2 = *reinterpret_cast<const bf16x8*>(bp + 64);

#pragma unroll
    for (int ct = 0; ct < 4; ++ct) {
      const unsigned short* ap = wcls + (size_t)(ct * KC + tap * 3) * 512;
      bf16x8 A0 = *reinterpret_cast<const bf16x8*>(ap);
      bf16x8 A1 = *reinterpret_cast<const bf16x8*>(ap + 512);
      bf16x8 A2 = *reinterpret_cast<const bf16x8*>(ap + 1024);
      f32x4 a = (ct == 0) ? acc0 : (ct == 1) ? acc1 : (ct == 2) ? acc2 : acc3;
      a = __builtin_amdgcn_mfma_f32_16x16x32_bf16(A0, B0, a, 0, 0, 0);
      a = __builtin_amdgcn_mfma_f32_16x16x32_bf16(A1, B1, a, 0, 0, 0);
      a = __builtin_amdgcn_mfma_f32_16x16x32_bf16(A2, B2, a, 0, 0, 0);
      if (ct == 0) acc0 = a; else if (ct == 1) acc1 = a;
      else if (ct == 2) acc2 = a; else acc3 = a;
    }
  }

  // epilogue: +cb, softmax over 64 couts (16 in-lane + lanes p,p+16,p+32,p+48)
  float m[16];
#pragma unroll
  for (int ct = 0; ct < 4; ++ct) {
    f32x4 cbv = *reinterpret_cast<const f32x4*>(cb + ct * 16 + l4 * 4);
    f32x4 a = (ct == 0) ? acc0 : (ct == 1) ? acc1 : (ct == 2) ? acc2 : acc3;
#pragma unroll
    for (int r = 0; r < 4; ++r) m[ct * 4 + r] = a[r] + cbv[r];
  }
  float mx = m[0];
#pragma unroll
  for (int i = 1; i < 16; ++i) mx = fmaxf(mx, m[i]);
  mx = fmaxf(mx, __shfl_xor(mx, 16));
  mx = fmaxf(mx, __shfl_xor(mx, 32));
  float sm = 0.0f;
#pragma unroll
  for (int i = 0; i < 16; ++i) { m[i] = __expf(m[i] - mx); sm += m[i]; }
  sm += __shfl_xor(sm, 16);
  sm += __shfl_xor(sm, 32);
  const float rs = 1.0f / sm;

  const int ow = 2 * (jbase + p15) + ((CLS == 1 || CLS == 3) ? 1 : 0);
  const bool valid = !((CLS == 1 || CLS == 3) && pt == 1 && p15 == 15);
  if (valid) {
    float* op = out + (size_t)(b * 64) * 3969 + oh * 63 + ow;
#pragma unroll
    for (int ct = 0; ct < 4; ++ct) {
#pragma unroll
      for (int r = 0; r < 4; ++r) {
        const int cout = ct * 16 + l4 * 4 + r;
        float sv = m[ct * 4 + r] * rs;
        float e2 = __expf(2.0f * sv);            // 2*tanh(s) = 2 - 4/(e^2s+1)
        op[(size_t)cout * 3969] = 2.0f - 4.0f / (e2 + 1.0f);
      }
    }
  }
}

extern "C" __global__ __launch_bounds__(256) void k_main(
    const float* __restrict__ ws, float* __restrict__ out) {
  const unsigned short* wpk = (const unsigned short*)ws;
  const float* cb = (const float*)((const char*)ws + CB_B);
  const unsigned short* panel = (const unsigned short*)((const char*)ws + PANEL_B);
  const int lane = threadIdx.x & 63;
  const int u = blockIdx.x * 4 +
                __builtin_amdgcn_readfirstlane((int)(threadIdx.x >> 6));
  // unit decode: EE[0,512) EO[512,1024) OE[1024,1520) OO[1520,2016)
  int cls, b, oh, ihA, ihB, pt;
  if (u < 1024) {
    cls = (u >= 512) ? 1 : 0;
    int t = u & 511;
    b = t >> 6; int r = (t >> 1) & 31; pt = t & 1;
    oh = 2 * r; ihA = r; ihB = r;
  } else {
    int v;
    if (u < 1520) { cls = 2; v = u - 1024; }
    else          { cls = 3; v = u - 1520; }
    b = v / 62; int s2 = v % 62;
    int rr = s2 >> 1; pt = s2 & 1;
    oh = 2 * rr + 1; ihA = rr + 1; ihB = rr;
  }
  if      (cls == 0) unit_body<0>(wpk, panel, cb, out, b, oh, ihA, ihB, pt, lane);
  else if (cls == 1) unit_body<1>(wpk, panel, cb, out, b, oh, ihA, ihB, pt, lane);
  else if (cls == 2) unit_body<2>(wpk, panel, cb, out, b, oh, ihA, ihB, pt, lane);
  else               unit_body<3>(wpk, panel, cb, out, b, oh, ihA, ihB, pt, lane);
}

extern "C" void kernel_launch(void* const* d_in, const int* in_sizes, int n_in,
                              void* d_out, int out_size, void* d_ws,
                              size_t ws_size, hipStream_t stream) {
  const float* x  = (const float*)d_in[0];
  const float* w  = (const float*)d_in[1];
  const float* cbi = (const float*)d_in[2];
  const float* bsi = (const float*)d_in[3];
  float* ws  = (float*)d_ws;
  float* out = (float*)d_out;

  hipLaunchKernelGGL(k_prep, dim3(264), dim3(256), 0, stream, x, w, cbi, bsi, ws);
  hipLaunchKernelGGL(k_main, dim3(504), dim3(256), 0, stream, ws, out);
}

// Round 9
// 81.085 us; speedup vs baseline: 1.4119x; 1.0012x over previous
//
#include <hip/hip_runtime.h>
#include <hip/hip_bf16.h>
#include <cstddef>

// B=8, Cin=32, D=16, H=W=32 -> ConvTranspose3d(32->64, k=3, s=2, p=1)
// -> mean over depth (D'=31) -> +bias -> softmax over C=64 -> tanh*2.
// Output (8, 64, 1, 63, 63) fp32.
//
// Depth-mean folds into weights: A0 = S - x[0] (kd=0), A1 = S (kd=1),
// A2 = S - x[15] (kd=2);  m = cb + sum_kd Tconv2d(A_kd, w/31).
// Parity classes (oh&1, ow&1): spatial taps NT = 1 (EE), 2 (EO), 2 (OE), 4 (OO);
// K = NT*96 (96 = 3 kd x 32 cin per tap).
//
// ROUND-9: round-8 (MFMA GEMM) landed 114->81us; top-5 dispatches are now all
// harness d_ws poison-fills (43us @ 6.2TB/s -- fixed floor ~49us). Remaining
// ~32us is k_prep+k_main+gaps. This round: fix k_prep panel-build occupancy
// (was 1 wave/SIMD, 16-deep serial HBM load chain): 512-thr blocks, depth
// halved across lane bit 3 (8 loads/thread, merge via shfl_xor(8)); dh=0
// lanes write A0/A1, dh=1 lanes write A2. k_main unchanged.

typedef __attribute__((ext_vector_type(8))) __bf16 bf16x8;
typedef __attribute__((ext_vector_type(4))) float f32x4;

namespace {
// ws byte layout
constexpr int WPACK_B = 0;         // bf16[55296]: EE@0 EO@6144 OE@18432 OO@30720
constexpr int CB_B    = 131072;    // f32[64]
constexpr int PANEL_B = 139264;    // bf16[8*32*32*96] = 1.5 MB
__device__ __constant__ int WOFF[4] = {0, 6144, 18432, 30720};
}

__device__ __forceinline__ uint f2bfu(float f) {
  __hip_bfloat16 h = __float2bfloat16(f);
  return (uint)*reinterpret_cast<unsigned short*>(&h);
}

// ---------------- prep: weight pack + panel build ----------------
extern "C" __global__ __launch_bounds__(512) void k_prep(
    const float* __restrict__ x, const float* __restrict__ w,
    const float* __restrict__ conv_bias, const float* __restrict__ bias,
    float* __restrict__ ws) {
  const int bid = blockIdx.x;
  const int tid = threadIdx.x;
  unsigned short* wpk = (unsigned short*)ws;
  float* cb = (float*)((char*)ws + CB_B);
  unsigned short* panel = (unsigned short*)((char*)ws + PANEL_B);

  if (bid < 8) {
    // ---- weight pack: t = cin*64 + cout over 2048 (first 256 thr/block) ----
    if (tid >= 256) return;
    int t = bid * 256 + tid;
    if (t < 64) cb[t] = conv_bias[t] + bias[t];
    const int cin = t >> 6, cout = t & 63;
    const float s = 1.0f / 31.0f;
    const float* src = w + t * 27;               // (Cin, Cout, kd, kh, kw)
    float wv[27];
#pragma unroll
    for (int i = 0; i < 27; ++i) wv[i] = src[i] * s;
    const int lane = ((cin >> 3) << 4) + (cout & 15);
    const int j = cin & 7;
    const int m16 = cout >> 4;
    // put(class, KC, tap, kd, value): frag-order index
    auto put = [&](int cls, int KC, int tap, int kd, float v) {
      int idx = WOFF[cls] + (((m16 * KC + tap * 3 + kd) * 64) + lane) * 8 + j;
      wpk[idx] = (unsigned short)f2bfu(v);
    };
#pragma unroll
    for (int kd = 0; kd < 3; ++kd) {
      put(0, 3,  0, kd, wv[kd * 9 + 4]);         // EE: (kh1,kw1)
      put(1, 6,  0, kd, wv[kd * 9 + 3]);         // EO tap0: kw0 (iw=j+1)
      put(1, 6,  1, kd, wv[kd * 9 + 5]);         // EO tap1: kw2 (iw=j)
      put(2, 6,  0, kd, wv[kd * 9 + 1]);         // OE tap0: kh0 (ihA)
      put(2, 6,  1, kd, wv[kd * 9 + 7]);         // OE tap1: kh2 (ihB)
      put(3, 12, 0, kd, wv[kd * 9 + 0]);         // OO: (kh0,kw0) ihA,j+1
      put(3, 12, 1, kd, wv[kd * 9 + 2]);         // OO: (kh0,kw2) ihA,j
      put(3, 12, 2, kd, wv[kd * 9 + 6]);         // OO: (kh2,kw0) ihB,j+1
      put(3, 12, 3, kd, wv[kd * 9 + 8]);         // OO: (kh2,kw2) ihB,j
    }
  } else {
    // ---- panel build: block = (b, ih); 512 thr, depth split on lane bit 3 --
    __shared__ float slds[3][32][33];
    const int p = bid - 8;
    const int b = p >> 5, ih = p & 31;
    {
      const int lane = tid & 63;
      const int wid  = tid >> 6;                 // 0..7
      const int w4   = lane & 7;                 // float4 column
      const int dh   = (lane >> 3) & 1;          // depth half
      const int cin  = wid * 4 + (lane >> 4);    // 0..31
      const float* xb =
          x + ((size_t)(b * 32 + cin) * 16 + dh * 8) * 1024 + ih * 32 + w4 * 4;
      float4 vv[8];
#pragma unroll
      for (int j = 0; j < 8; ++j) vv[j] = *(const float4*)(xb + j * 1024);
      float sx = 0.f, sy = 0.f, sz = 0.f, sw = 0.f;
#pragma unroll
      for (int j = 0; j < 8; ++j) { sx += vv[j].x; sy += vv[j].y; sz += vv[j].z; sw += vv[j].w; }
      // merge depth halves (partner = lane ^ 8)
      sx += __shfl_xor(sx, 8);
      sy += __shfl_xor(sy, 8);
      sz += __shfl_xor(sz, 8);
      sw += __shfl_xor(sw, 8);
      const int c0 = w4 * 4;
      if (dh == 0) {                             // owns d=0 (vv[0])
        slds[0][cin][c0 + 0] = sx - vv[0].x;  slds[1][cin][c0 + 0] = sx;
        slds[0][cin][c0 + 1] = sy - vv[0].y;  slds[1][cin][c0 + 1] = sy;
        slds[0][cin][c0 + 2] = sz - vv[0].z;  slds[1][cin][c0 + 2] = sz;
        slds[0][cin][c0 + 3] = sw - vv[0].w;  slds[1][cin][c0 + 3] = sw;
      } else {                                   // owns d=15 (vv[7])
        slds[2][cin][c0 + 0] = sx - vv[7].x;
        slds[2][cin][c0 + 1] = sy - vv[7].y;
        slds[2][cin][c0 + 2] = sz - vv[7].z;
        slds[2][cin][c0 + 3] = sw - vv[7].w;
      }
    }
    __syncthreads();
    {
      const int iw = tid >> 4, g = tid & 15;     // 16 threads cover 96 bf16/row
      uint* dst = (uint*)(panel + ((size_t)((b * 32 + ih) * 32) + iw) * 96) + g * 3;
#pragma unroll
      for (int mm = 0; mm < 3; ++mm) {
        int k0 = g * 6 + mm * 2;
        uint lo = f2bfu(slds[k0 >> 5][k0 & 31][iw]);
        uint hi = f2bfu(slds[(k0 + 1) >> 5][(k0 + 1) & 31][iw]);
        dst[mm] = lo | (hi << 16);
      }
    }
  }
}

// ---------------- main: one wave per 16-pixel tile ----------------
template <int CLS>
__device__ __forceinline__ void unit_body(const unsigned short* __restrict__ wpk,
                                          const unsigned short* __restrict__ panel,
                                          const float* __restrict__ cb,
                                          float* __restrict__ out,
                                          int b, int oh, int ihA, int ihB,
                                          int pt, int lane) {
  constexpr int NT = (CLS == 0) ? 1 : (CLS == 3 ? 4 : 2);
  constexpr int KC = NT * 3;
  const int p15 = lane & 15, l4 = lane >> 4;
  const int jbase = pt * 16;
  const int laneB = p15 * 96 + l4 * 8;           // bf16 units within panel rows
  const unsigned short* wcls = wpk + WOFF[CLS] + lane * 8;

  f32x4 acc0 = {0,0,0,0}, acc1 = {0,0,0,0}, acc2 = {0,0,0,0}, acc3 = {0,0,0,0};

#pragma unroll
  for (int tap = 0; tap < NT; ++tap) {
    int ih, jo;
    if      constexpr (CLS == 0) { ih = ihA; jo = 0; }
    else if constexpr (CLS == 1) { ih = ihA; jo = (tap == 0) ? 1 : 0; }
    else if constexpr (CLS == 2) { ih = (tap == 0) ? ihA : ihB; jo = 0; }
    else { ih = (tap < 2) ? ihA : ihB; jo = (tap & 1) ? 0 : 1; }

    const unsigned short* bp =
        panel + ((size_t)((b * 32 + ih) * 32) + jbase + jo) * 96 + laneB;
    bf16x8 B0 = *reinterpret_cast<const bf16x8*>(bp);
    bf16x8 B1 = *reinterpret_cast<const bf16x8*>(bp + 32);
    bf16x8 B2 = *reinterpret_cast<const bf16x8*>(bp + 64);

#pragma unroll
    for (int ct = 0; ct < 4; ++ct) {
      const unsigned short* ap = wcls + (size_t)(ct * KC + tap * 3) * 512;
      bf16x8 A0 = *reinterpret_cast<const bf16x8*>(ap);
      bf16x8 A1 = *reinterpret_cast<const bf16x8*>(ap + 512);
      bf16x8 A2 = *reinterpret_cast<const bf16x8*>(ap + 1024);
      f32x4 a = (ct == 0) ? acc0 : (ct == 1) ? acc1 : (ct == 2) ? acc2 : acc3;
      a = __builtin_amdgcn_mfma_f32_16x16x32_bf16(A0, B0, a, 0, 0, 0);
      a = __builtin_amdgcn_mfma_f32_16x16x32_bf16(A1, B1, a, 0, 0, 0);
      a = __builtin_amdgcn_mfma_f32_16x16x32_bf16(A2, B2, a, 0, 0, 0);
      if (ct == 0) acc0 = a; else if (ct == 1) acc1 = a;
      else if (ct == 2) acc2 = a; else acc3 = a;
    }
  }

  // epilogue: +cb, softmax over 64 couts (16 in-lane + lanes p,p+16,p+32,p+48)
  float m[16];
#pragma unroll
  for (int ct = 0; ct < 4; ++ct) {
    f32x4 cbv = *reinterpret_cast<const f32x4*>(cb + ct * 16 + l4 * 4);
    f32x4 a = (ct == 0) ? acc0 : (ct == 1) ? acc1 : (ct == 2) ? acc2 : acc3;
#pragma unroll
    for (int r = 0; r < 4; ++r) m[ct * 4 + r] = a[r] + cbv[r];
  }
  float mx = m[0];
#pragma unroll
  for (int i = 1; i < 16; ++i) mx = fmaxf(mx, m[i]);
  mx = fmaxf(mx, __shfl_xor(mx, 16));
  mx = fmaxf(mx, __shfl_xor(mx, 32));
  float sm = 0.0f;
#pragma unroll
  for (int i = 0; i < 16; ++i) { m[i] = __expf(m[i] - mx); sm += m[i]; }
  sm += __shfl_xor(sm, 16);
  sm += __shfl_xor(sm, 32);
  const float rs = 1.0f / sm;

  const int ow = 2 * (jbase + p15) + ((CLS == 1 || CLS == 3) ? 1 : 0);
  const bool valid = !((CLS == 1 || CLS == 3) && pt == 1 && p15 == 15);
  if (valid) {
    float* op = out + (size_t)(b * 64) * 3969 + oh * 63 + ow;
#pragma unroll
    for (int ct = 0; ct < 4; ++ct) {
#pragma unroll
      for (int r = 0; r < 4; ++r) {
        const int cout = ct * 16 + l4 * 4 + r;
        float sv = m[ct * 4 + r] * rs;
        float e2 = __expf(2.0f * sv);            // 2*tanh(s) = 2 - 4/(e^2s+1)
        op[(size_t)cout * 3969] = 2.0f - 4.0f / (e2 + 1.0f);
      }
    }
  }
}

extern "C" __global__ __launch_bounds__(256) void k_main(
    const float* __restrict__ ws, float* __restrict__ out) {
  const unsigned short* wpk = (const unsigned short*)ws;
  const float* cb = (const float*)((const char*)ws + CB_B);
  const unsigned short* panel = (const unsigned short*)((const char*)ws + PANEL_B);
  const int lane = threadIdx.x & 63;
  const int u = blockIdx.x * 4 +
                __builtin_amdgcn_readfirstlane((int)(threadIdx.x >> 6));
  // unit decode: EE[0,512) EO[512,1024) OE[1024,1520) OO[1520,2016)
  int cls, b, oh, ihA, ihB, pt;
  if (u < 1024) {
    cls = (u >= 512) ? 1 : 0;
    int t = u & 511;
    b = t >> 6; int r = (t >> 1) & 31; pt = t & 1;
    oh = 2 * r; ihA = r; ihB = r;
  } else {
    int v;
    if (u < 1520) { cls = 2; v = u - 1024; }
    else          { cls = 3; v = u - 1520; }
    b = v / 62; int s2 = v % 62;
    int rr = s2 >> 1; pt = s2 & 1;
    oh = 2 * rr + 1; ihA = rr + 1; ihB = rr;
  }
  if      (cls == 0) unit_body<0>(wpk, panel, cb, out, b, oh, ihA, ihB, pt, lane);
  else if (cls == 1) unit_body<1>(wpk, panel, cb, out, b, oh, ihA, ihB, pt, lane);
  else if (cls == 2) unit_body<2>(wpk, panel, cb, out, b, oh, ihA, ihB, pt, lane);
  else               unit_body<3>(wpk, panel, cb, out, b, oh, ihA, ihB, pt, lane);
}

extern "C" void kernel_launch(void* const* d_in, const int* in_sizes, int n_in,
                              void* d_out, int out_size, void* d_ws,
                              size_t ws_size, hipStream_t stream) {
  const float* x  = (const float*)d_in[0];
  const float* w  = (const float*)d_in[1];
  const float* cbi = (const float*)d_in[2];
  const float* bsi = (const float*)d_in[3];
  float* ws  = (float*)d_ws;
  float* out = (float*)d_out;

  hipLaunchKernelGGL(k_prep, dim3(264), dim3(512), 0, stream, x, w, cbi, bsi, ws);
  hipLaunchKernelGGL(k_main, dim3(504), dim3(256), 0, stream, ws, out);
}

// Round 10
// 78.186 us; speedup vs baseline: 1.4642x; 1.0371x over previous
//
#include <hip/hip_runtime.h>
#include <hip/hip_bf16.h>
#include <cstddef>

// B=8, Cin=32, D=16, H=W=32 -> ConvTranspose3d(32->64, k=3, s=2, p=1)
// -> mean over depth (D'=31) -> +bias -> softmax over C=64 -> tanh*2.
// Output (8, 64, 1, 63, 63) fp32.
//
// Depth-mean folds into weights: A0 = S - x[0] (kd=0), A1 = S (kd=1),
// A2 = S - x[15] (kd=2);  m = cb + sum_kd Tconv2d(A_kd, w/31).
// Parity classes (oh&1, ow&1): taps NT = 1 (EE), 2 (EO), 2 (OE), 4 (OO).
//
// ROUND-10: FULL FUSION, single kernel, zero workspace. R9 showed both
// kernels below the 43us d_ws poison-fill (harness floor ~50us); remaining
// ~31us = kernels + dispatch gaps + panel round-trip. Now one kernel:
// block = (b, rr): [1] weight-pack into LDS (redundant per block, w is
// L2-cached), [2] panel rows rr,rr+1 into LDS (direct from x, depth-reduce
// in-reg), [3] one barrier, 8 waves = (class x pt) MFMA units, A+B frags
// via ds_read_b128. LDS 123.6KB dynamic -> 1 block/CU, 256 blocks = 256 CUs.
// Frag layouts (m89-verified): A: m=lane&15, k=(lane>>4)*8+j; B: n=lane&15,
// same k; D: col(n)=lane&15, row(m)=(lane>>4)*4+reg.

typedef __attribute__((ext_vector_type(8))) __bf16 bf16x8;
typedef __attribute__((ext_vector_type(4))) float f32x4;

namespace {
constexpr int WTAB_SH  = 55296;        // bf16: EE@0 EO@6144 OE@18432 OO@30720
constexpr int PROW_SH  = 3200;         // bf16 per panel row (3072 + 128 pad)
constexpr int WTAB_B   = WTAB_SH * 2;              // 110592
constexpr int PANEL_B  = WTAB_B;                   // panels start
constexpr int CB_B     = WTAB_B + 2 * PROW_SH * 2; // 123392
constexpr int LDS_B    = CB_B + 64 * 4;            // 123648
__device__ __constant__ int WOFF[4] = {0, 6144, 18432, 30720};
}

__device__ __forceinline__ unsigned short f2bfu(float f) {
  __hip_bfloat16 h = __float2bfloat16(f);
  return *reinterpret_cast<unsigned short*>(&h);
}

// ---------------- MFMA unit (operands in LDS) ----------------
template <int CLS>
__device__ __forceinline__ void unit_lds(const unsigned short* __restrict__ wtab,
                                         const unsigned short* __restrict__ panels,
                                         const float* __restrict__ cbl,
                                         float* __restrict__ out,
                                         int b, int rr, int pt, int lane) {
  constexpr int NT = (CLS == 0) ? 1 : (CLS == 3 ? 4 : 2);
  constexpr int KC = NT * 3;
  const int p15 = lane & 15, l4 = lane >> 4;
  const int jbase = pt * 16;
  const int oh = (CLS < 2) ? 2 * rr : 2 * rr + 1;

  f32x4 acc0 = {0,0,0,0}, acc1 = {0,0,0,0}, acc2 = {0,0,0,0}, acc3 = {0,0,0,0};

#pragma unroll
  for (int tap = 0; tap < NT; ++tap) {
    int lrow, jo;                                 // local panel row, iw offset
    if      constexpr (CLS == 0) { lrow = 0; jo = 0; }
    else if constexpr (CLS == 1) { lrow = 0; jo = (tap == 0) ? 1 : 0; }
    else if constexpr (CLS == 2) { lrow = (tap == 0) ? 1 : 0; jo = 0; }
    else { lrow = (tap < 2) ? 1 : 0; jo = (tap & 1) ? 0 : 1; }

    const unsigned short* bp =
        panels + lrow * PROW_SH + (jbase + jo + p15) * 96 + l4 * 8;
    bf16x8 B0 = *reinterpret_cast<const bf16x8*>(bp);
    bf16x8 B1 = *reinterpret_cast<const bf16x8*>(bp + 32);
    bf16x8 B2 = *reinterpret_cast<const bf16x8*>(bp + 64);

#pragma unroll
    for (int ct = 0; ct < 4; ++ct) {
      const unsigned short* ap =
          wtab + WOFF[CLS] + (size_t)(ct * KC + tap * 3) * 512 + lane * 8;
      bf16x8 A0 = *reinterpret_cast<const bf16x8*>(ap);
      bf16x8 A1 = *reinterpret_cast<const bf16x8*>(ap + 512);
      bf16x8 A2 = *reinterpret_cast<const bf16x8*>(ap + 1024);
      f32x4 a = (ct == 0) ? acc0 : (ct == 1) ? acc1 : (ct == 2) ? acc2 : acc3;
      a = __builtin_amdgcn_mfma_f32_16x16x32_bf16(A0, B0, a, 0, 0, 0);
      a = __builtin_amdgcn_mfma_f32_16x16x32_bf16(A1, B1, a, 0, 0, 0);
      a = __builtin_amdgcn_mfma_f32_16x16x32_bf16(A2, B2, a, 0, 0, 0);
      if (ct == 0) acc0 = a; else if (ct == 1) acc1 = a;
      else if (ct == 2) acc2 = a; else acc3 = a;
    }
  }

  // epilogue: +cb, softmax over 64 couts (16 in-lane + lanes p,p+16,p+32,p+48)
  float m[16];
#pragma unroll
  for (int ct = 0; ct < 4; ++ct) {
    f32x4 cbv = *reinterpret_cast<const f32x4*>(cbl + ct * 16 + l4 * 4);
    f32x4 a = (ct == 0) ? acc0 : (ct == 1) ? acc1 : (ct == 2) ? acc2 : acc3;
#pragma unroll
    for (int r = 0; r < 4; ++r) m[ct * 4 + r] = a[r] + cbv[r];
  }
  float mx = m[0];
#pragma unroll
  for (int i = 1; i < 16; ++i) mx = fmaxf(mx, m[i]);
  mx = fmaxf(mx, __shfl_xor(mx, 16));
  mx = fmaxf(mx, __shfl_xor(mx, 32));
  float sm = 0.0f;
#pragma unroll
  for (int i = 0; i < 16; ++i) { m[i] = __expf(m[i] - mx); sm += m[i]; }
  sm += __shfl_xor(sm, 16);
  sm += __shfl_xor(sm, 32);
  const float rs = 1.0f / sm;

  const int ow = 2 * (jbase + p15) + ((CLS == 1 || CLS == 3) ? 1 : 0);
  const bool valid = !((CLS == 1 || CLS == 3) && pt == 1 && p15 == 15);
  if (valid) {
    float* op = out + (size_t)(b * 64) * 3969 + oh * 63 + ow;
#pragma unroll
    for (int ct = 0; ct < 4; ++ct) {
#pragma unroll
      for (int r = 0; r < 4; ++r) {
        const int cout = ct * 16 + l4 * 4 + r;
        float sv = m[ct * 4 + r] * rs;
        float e2 = __expf(2.0f * sv);            // 2*tanh(s) = 2 - 4/(e^2s+1)
        op[(size_t)cout * 3969] = 2.0f - 4.0f / (e2 + 1.0f);
      }
    }
  }
}

// ---------------- fused kernel ----------------
extern "C" __global__ __launch_bounds__(512) void k_all(
    const float* __restrict__ x, const float* __restrict__ w,
    const float* __restrict__ conv_bias, const float* __restrict__ bias,
    float* __restrict__ out) {
  extern __shared__ char smem[];
  unsigned short* wtab   = (unsigned short*)smem;
  unsigned short* panels = (unsigned short*)(smem + PANEL_B);
  float*          cbl    = (float*)(smem + CB_B);

  const int rr = blockIdx.x;                      // 0..31 (row pair)
  const int b  = blockIdx.y;                      // 0..7
  const int tid = threadIdx.x;

  // ---- phase 1: weight pack into LDS (redundant per block) ----
#pragma unroll
  for (int k = 0; k < 4; ++k) {
    const int t = tid + k * 512;                  // cin*64 + cout
    if (t < 64) cbl[t] = conv_bias[t] + bias[t];
    const int cin = t >> 6, cout = t & 63;
    const float s = 1.0f / 31.0f;
    const float* src = w + t * 27;                // (Cin, Cout, kd, kh, kw)
    float wv[27];
#pragma unroll
    for (int i = 0; i < 27; ++i) wv[i] = src[i] * s;
    const int lane = ((cin >> 3) << 4) + (cout & 15);
    const int j = cin & 7;
    const int m16 = cout >> 4;
    auto put = [&](int cls, int KC, int tap, int kd, float v) {
      wtab[WOFF[cls] + (((m16 * KC + tap * 3 + kd) * 64) + lane) * 8 + j] = f2bfu(v);
    };
#pragma unroll
    for (int kd = 0; kd < 3; ++kd) {
      put(0, 3,  0, kd, wv[kd * 9 + 4]);          // EE: (kh1,kw1)
      put(1, 6,  0, kd, wv[kd * 9 + 3]);          // EO tap0: kw0 (iw=j+1)
      put(1, 6,  1, kd, wv[kd * 9 + 5]);          // EO tap1: kw2 (iw=j)
      put(2, 6,  0, kd, wv[kd * 9 + 1]);          // OE tap0: kh0 (row rr+1)
      put(2, 6,  1, kd, wv[kd * 9 + 7]);          // OE tap1: kh2 (row rr)
      put(3, 12, 0, kd, wv[kd * 9 + 0]);          // OO: (kh0,kw0)
      put(3, 12, 1, kd, wv[kd * 9 + 2]);          // OO: (kh0,kw2)
      put(3, 12, 2, kd, wv[kd * 9 + 6]);          // OO: (kh2,kw0)
      put(3, 12, 3, kd, wv[kd * 9 + 8]);          // OO: (kh2,kw2)
    }
  }

  // ---- phase 2: panel rows rr, rr+1 into LDS (depth reduce in-reg) ----
  {
    const int row = tid >> 8;                     // 0..1
    const int r2 = tid & 255;
    const int cin = r2 >> 3, w4 = r2 & 7;
    const int ih = rr + row;
    if (ih < 32) {
      const float* xb = x + ((size_t)(b * 32 + cin) * 16) * 1024 + ih * 32 + w4 * 4;
      float4 vv[16];
#pragma unroll
      for (int d = 0; d < 16; ++d) vv[d] = *(const float4*)(xb + d * 1024);
      float S[4] = {0.f, 0.f, 0.f, 0.f};
#pragma unroll
      for (int d = 0; d < 16; ++d) {
        S[0] += vv[d].x; S[1] += vv[d].y; S[2] += vv[d].z; S[3] += vv[d].w;
      }
      const float d0[4]  = {vv[0].x, vv[0].y, vv[0].z, vv[0].w};
      const float d15[4] = {vv[15].x, vv[15].y, vv[15].z, vv[15].w};
      unsigned short* pr = panels + row * PROW_SH;
#pragma unroll
      for (int c = 0; c < 4; ++c) {
        const int base = (w4 * 4 + c) * 96 + cin;
        pr[base]      = f2bfu(S[c] - d0[c]);      // kd=0 (drops d=0)
        pr[base + 32] = f2bfu(S[c]);              // kd=1
        pr[base + 64] = f2bfu(S[c] - d15[c]);     // kd=2 (drops d=15)
      }
    }
  }
  __syncthreads();

  // ---- phase 3: 8 waves = (class, pt) MFMA units ----
  const int wid  = __builtin_amdgcn_readfirstlane(tid >> 6);   // 0..7
  const int lane = tid & 63;
  const int cls = wid >> 1, pt = wid & 1;
  if (rr == 31 && cls >= 2) return;               // no odd oh=63
  if      (cls == 0) unit_lds<0>(wtab, panels, cbl, out, b, rr, pt, lane);
  else if (cls == 1) unit_lds<1>(wtab, panels, cbl, out, b, rr, pt, lane);
  else if (cls == 2) unit_lds<2>(wtab, panels, cbl, out, b, rr, pt, lane);
  else               unit_lds<3>(wtab, panels, cbl, out, b, rr, pt, lane);
}

extern "C" void kernel_launch(void* const* d_in, const int* in_sizes, int n_in,
                              void* d_out, int out_size, void* d_ws,
                              size_t ws_size, hipStream_t stream) {
  const float* x   = (const float*)d_in[0];
  const float* w   = (const float*)d_in[1];
  const float* cbi = (const float*)d_in[2];
  const float* bsi = (const float*)d_in[3];
  float* out = (float*)d_out;

  static bool attr_set = false;                   // host-side, capture-safe
  if (!attr_set) {
    (void)hipFuncSetAttribute((const void*)k_all,
                              hipFuncAttributeMaxDynamicSharedMemorySize, LDS_B);
    attr_set = true;
  }
  hipLaunchKernelGGL(k_all, dim3(32, 8), dim3(512), LDS_B, stream,
                     x, w, cbi, bsi, out);
}